// Round 1
// 507.026 us; speedup vs baseline: 1.0516x; 1.0516x over previous
//
#include <hip/hip_runtime.h>

// S4 layer, MI355X. B=16, T=2048, H=1024, N=64.
// Pipeline:
//   k0          : B_bar = B*exp(ldt) -> bf16, C -> bf16 (one-time precompute)
//   k1          : blocks 0,1 -> Taylor expm(M) / expm(64*M) (1 wave each, bf16 MFMA)
//                 blocks 2.. -> u = x @ B_bar^T, LDS-free: direct reg-fragment MFMA
//   scan_local  : 32 chunks x 64 steps, zero-init local scans -> F_c   (I+R MFMA step)
//   scan_chunks : 1 wave, 32-step scan over chunk boundaries with A_L -> P_c
//   scan_final  : re-run chunks with init P_c, write all states bf16 (T,B,N)
//   out_proj    : out = states @ C^T + D*x, LDS-free reg-fragment MFMA
// ws map (floats): [0]A_bar(4096) [4096]A_L(4096)
//                  [8192]F(32768)  <-- ALIASED by Bbf bf16 (k0->k1, dead until scan_local)
//                  [40960]P(32768) [73728]u(2097152, layout (T,B,N) fp32)
//                  [2170880]states bf16 (lower 1M floats of 2M region)
//                  [3219456]Cbf bf16 (upper half of states region, 32768 floats)

#define H   1024
#define NS  64
#define NB  16
#define TT  2048
#define LCH 64
#define KCH 32

typedef __attribute__((ext_vector_type(8))) short bf16x8;
typedef __attribute__((ext_vector_type(4))) float f32x4;
typedef __attribute__((ext_vector_type(2))) unsigned int u32x2;

#define WS_ABAR 0
#define WS_AL   4096
#define WS_F    8192
#define WS_P    40960
#define WS_U    73728
#define WS_S    2170880
#define WS_BBF  8192      // aliases F region: written by k0, read by k1, dead before scan_local writes F
#define WS_CBF  3219456   // upper half of states region (states bf16 only needs lower half)

__device__ __forceinline__ unsigned short f2bf(float x) {
  union { float f; unsigned u; } v; v.f = x;
  unsigned r = (v.u + 0x7FFFu + ((v.u >> 16) & 1u)) >> 16;   // RNE
  return (unsigned short)r;
}

__device__ __forceinline__ bf16x8 packbf8(f32x4 a, f32x4 b) {
  bf16x8 r;
  r[0] = (short)f2bf(a[0]); r[1] = (short)f2bf(a[1]);
  r[2] = (short)f2bf(a[2]); r[3] = (short)f2bf(a[3]);
  r[4] = (short)f2bf(b[0]); r[5] = (short)f2bf(b[1]);
  r[6] = (short)f2bf(b[2]); r[7] = (short)f2bf(b[3]);
  return r;
}

__device__ __forceinline__ u32x2 packbf4(f32x4 v) {
  u32x2 r;
  r[0] = (unsigned)f2bf(v[0]) | ((unsigned)f2bf(v[1]) << 16);
  r[1] = (unsigned)f2bf(v[2]) | ((unsigned)f2bf(v[3]) << 16);
  return r;
}

__device__ __forceinline__ f32x4 mfma16(bf16x8 a, bf16x8 b, f32x4 c) {
  // D[m][n] = sum_k A[m][k]*B[k][n] + C.
  // A: lane holds A[m=lane&15][k=(lane>>4)*8+j]; B: B[k=(lane>>4)*8+j][n=lane&15];
  // C/D: col=lane&15, row=(lane>>4)*4+reg   (guide-verified layouts)
  return __builtin_amdgcn_mfma_f32_16x16x32_bf16(a, b, c, 0, 0, 0);
}

// ---------------- k0: one-time bf16 precompute of B_bar and C ----------------
__global__ __launch_bounds__(256) void k0(const float* Bm, const float* Cm,
                                          const float* ldt, float* ws) {
  short* Bbf = (short*)(ws + WS_BBF);   // Bbf[n][h] = bf16(B[n][h]*exp(ldt[h]))
  short* Cbf = (short*)(ws + WS_CBF);   // Cbf[h][n] = bf16(C[h][n])
  const int idx = (blockIdx.x * 256 + threadIdx.x) * 4;   // grid 64 -> 65536 elems
  f32x4 b = *(const f32x4*)(Bm + idx);
  f32x4 l = *(const f32x4*)(ldt + (idx & (H - 1)));
  f32x4 bb;
  for (int j = 0; j < 4; ++j) bb[j] = b[j] * expf(l[j]);
  *(u32x2*)&Bbf[idx] = packbf4(bb);
  f32x4 c = *(const f32x4*)(Cm + idx);
  *(u32x2*)&Cbf[idx] = packbf4(c);
}

// ---------------- prep: E = expm(scale*A), 1 wave, Taylor-12 via bf16 MFMA ----------------
__device__ void prep_block(const float* Ain, const float* ldt, float* ws, int which) {
  __shared__ float Mb[64 * 68];   // Mb[n][k] = M[k][n]  (B-operand view, +pad)
  __shared__ short Tl[64 * 72];   // current term, A-layout [m][k] bf16 (+pad)
  const int lane = threadIdx.x;
  const int cq = lane >> 4, cl = lane & 15;

  float s = 0.f;
  for (int j = 0; j < 16; ++j) s += expf(ldt[lane + j * 64]);
  for (int off = 32; off; off >>= 1) s += __shfl_down(s, off);
  float dtm = __shfl(s, 0) * (1.0f / 1024.0f);
  float scale = which ? dtm * (float)LCH : dtm;

  for (int idx = lane; idx < 4096; idx += 64) {
    int r = idx >> 6, c = idx & 63;
    float v = Ain[idx] * scale;
    Mb[c * 68 + r] = v;
    Tl[r * 72 + c] = (short)f2bf(v);       // term1 = M
  }

  float E[16][4];                           // C/D-layout accumulator, fp32
  for (int mt = 0; mt < 4; ++mt)
    for (int nt = 0; nt < 4; ++nt)
      for (int r = 0; r < 4; ++r) {
        int row = mt * 16 + cq * 4 + r, col = nt * 16 + cl;
        E[mt * 4 + nt][r] = (row == col ? 1.f : 0.f) + Ain[row * 64 + col] * scale;
      }

  __asm volatile("s_waitcnt lgkmcnt(0)" ::: "memory");

  for (int it = 2; it <= 12; ++it) {
    bf16x8 af[4][2];
    for (int mt = 0; mt < 4; ++mt)
      for (int kh = 0; kh < 2; ++kh)
        af[mt][kh] = *(const bf16x8*)&Tl[(mt * 16 + cl) * 72 + kh * 32 + cq * 8];
    float inv = 1.0f / (float)it;
    bf16x8 bfr[4][2];
    for (int nt = 0; nt < 4; ++nt)
      for (int kh = 0; kh < 2; ++kh) {
        const float* p = &Mb[(nt * 16 + cl) * 68 + kh * 32 + cq * 8];
        f32x4 a = *(const f32x4*)p;
        f32x4 b = *(const f32x4*)(p + 4);
        bfr[nt][kh] = packbf8(a * inv, b * inv);
      }
    f32x4 zero = {0.f, 0.f, 0.f, 0.f};
    f32x4 acc[16];
    for (int i = 0; i < 16; ++i) acc[i] = zero;
    for (int mt = 0; mt < 4; ++mt)
      for (int nt = 0; nt < 4; ++nt) {
        acc[mt * 4 + nt] = mfma16(af[mt][0], bfr[nt][0], acc[mt * 4 + nt]);
        acc[mt * 4 + nt] = mfma16(af[mt][1], bfr[nt][1], acc[mt * 4 + nt]);
      }
    __asm volatile("s_waitcnt lgkmcnt(0)" ::: "memory");
    for (int mt = 0; mt < 4; ++mt)
      for (int nt = 0; nt < 4; ++nt)
        for (int r = 0; r < 4; ++r) {
          float t = acc[mt * 4 + nt][r];
          E[mt * 4 + nt][r] += t;
          Tl[(mt * 16 + cq * 4 + r) * 72 + nt * 16 + cl] = (short)f2bf(t);
        }
    __asm volatile("s_waitcnt lgkmcnt(0)" ::: "memory");
  }

  float* dst = ws + (which ? WS_AL : WS_ABAR);
  for (int mt = 0; mt < 4; ++mt)
    for (int nt = 0; nt < 4; ++nt)
      for (int r = 0; r < 4; ++r)
        dst[(mt * 16 + cq * 4 + r) * 64 + nt * 16 + cl] = E[mt * 4 + nt][r];
}

// ---------------- u = x @ B_bar^T : LDS-free, direct register fragments ----------------
// Per block: 64 bt rows, full N=64. 4 waves, each owns 16 bt.
// A-frag straight from global x (fp32 -> bf16 in reg); B-frag straight from Bbf (L2-resident).
__device__ void gemm_u(const float* x, const float* ws, float* u2, int bid) {
  const short* Bbf = (const short*)(ws + WS_BBF);
  const int tid = threadIdx.x;
  const int wid = tid >> 6, lane = tid & 63;
  const int cq = lane >> 4, cl = lane & 15;
  const int bt0 = bid * 64 + wid * 16;

  const float* xr = x + (long)(bt0 + cl) * H + cq * 8;   // A rows: m = cl
  const short* br = Bbf + cq * 8;

  f32x4 zero = {0.f, 0.f, 0.f, 0.f};
  f32x4 acc[4];
  for (int i = 0; i < 4; ++i) acc[i] = zero;

#pragma unroll 4
  for (int ks = 0; ks < 32; ++ks) {
    const int k0 = ks * 32;
    f32x4 xa = *(const f32x4*)(xr + k0);
    f32x4 xb = *(const f32x4*)(xr + k0 + 4);
    bf16x8 af = packbf8(xa, xb);
    for (int nt = 0; nt < 4; ++nt) {
      bf16x8 bf = *(const bf16x8*)(br + (nt * 16 + cl) * H + k0);   // B: n = cl
      acc[nt] = mfma16(af, bf, acc[nt]);
    }
  }

  for (int nt = 0; nt < 4; ++nt)
    for (int r = 0; r < 4; ++r) {
      int obt = bt0 + cq * 4 + r;                 // C/D rows: m = cq*4+r
      int t = obt & (TT - 1), b = obt >> 11;
      u2[(long)(t * 16 + b) * 64 + nt * 16 + cl] = acc[nt][r];
    }
}

__global__ __launch_bounds__(256) void k1(const float* x, const float* Ain,
                                          const float* ldt, float* ws) {
  if (blockIdx.x < 2) {
    if (threadIdx.x < 64) prep_block(Ain, ldt, ws, blockIdx.x);
    return;
  }
  gemm_u(x, ws, ws + WS_U, blockIdx.x - 2);
}

// ---------------- scan step: Z_new = (I+R) @ Z + U, transposed (Z is N x B) ----------------
__device__ __forceinline__ void load_RF(const float* Amat, bf16x8 Rf[4][2], int cq, int cl) {
  for (int mt = 0; mt < 4; ++mt)
    for (int kh = 0; kh < 2; ++kh) {
      int m = mt * 16 + cl;
      int kb = kh * 32 + cq * 8;
      f32x4 v0 = *(const f32x4*)&Amat[m * 64 + kb];
      f32x4 v1 = *(const f32x4*)&Amat[m * 64 + kb + 4];
      for (int j = 0; j < 4; ++j) {
        if (m == kb + j) v0[j] -= 1.f;          // R = A_bar - I
        if (m == kb + 4 + j) v1[j] -= 1.f;
      }
      Rf[mt][kh] = packbf8(v0, v1);
    }
}

// Single wave. Z[4] f32x4 in C/D layout: per lane state index i = tile*16+cq*4+reg, batch b=cl.
__device__ __forceinline__ void scan_step(f32x4 Z[4], const bf16x8 Rf[4][2], short* Zl,
                                          const f32x4 U[4], int cq, int cl) {
  for (int t = 0; t < 4; ++t)
    *(u32x2*)&Zl[cl * 72 + t * 16 + cq * 4] = packbf4(Z[t]);   // old Z -> bf16 LDS
  __asm volatile("s_waitcnt lgkmcnt(0)" ::: "memory");
  bf16x8 zf0 = *(const bf16x8*)&Zl[cl * 72 + cq * 8];
  bf16x8 zf1 = *(const bf16x8*)&Zl[cl * 72 + 32 + cq * 8];
  for (int t = 0; t < 4; ++t) Z[t] += U[t];                    // identity path + input, fp32
  for (int mt = 0; mt < 4; ++mt) {
    Z[mt] = mfma16(Rf[mt][0], zf0, Z[mt]);                     // += R @ Z_old
    Z[mt] = mfma16(Rf[mt][1], zf1, Z[mt]);
  }
}

__global__ __launch_bounds__(64) void scan_local_k(float* ws) {
  const float* Abar = ws + WS_ABAR;
  const float* u2 = ws + WS_U;
  float* F = ws + WS_F;
  __shared__ short Zl[16 * 72];
  const int lane = threadIdx.x, cq = lane >> 4, cl = lane & 15;
  const int c = blockIdx.x;
  bf16x8 Rf[4][2];
  load_RF(Abar, Rf, cq, cl);
  f32x4 zero = {0.f, 0.f, 0.f, 0.f};
  f32x4 Z[4], U[4], Un[4];
  for (int t = 0; t < 4; ++t) Z[t] = zero;
  const float* ub = u2 + (long)c * LCH * 1024 + cl * 64 + cq * 4;
  for (int t = 0; t < 4; ++t) U[t] = *(const f32x4*)(ub + t * 16);
  for (int ti = 0; ti < LCH; ++ti) {
    const float* un = ub + (ti + 1) * 1024;   // prefetch (last iter reads scratch: harmless)
    for (int t = 0; t < 4; ++t) Un[t] = *(const f32x4*)(un + t * 16);
    scan_step(Z, Rf, Zl, U, cq, cl);
    for (int t = 0; t < 4; ++t) U[t] = Un[t];
  }
  for (int t = 0; t < 4; ++t)
    *(f32x4*)&F[(long)c * 1024 + cl * 64 + t * 16 + cq * 4] = Z[t];
}

__global__ __launch_bounds__(64) void scan_chunks_k(float* ws) {
  const float* AL = ws + WS_AL;
  const float* F = ws + WS_F;
  float* P = ws + WS_P;
  __shared__ short Zl[16 * 72];
  const int lane = threadIdx.x, cq = lane >> 4, cl = lane & 15;
  bf16x8 Rf[4][2];
  load_RF(AL, Rf, cq, cl);
  f32x4 zero = {0.f, 0.f, 0.f, 0.f};
  f32x4 Z[4], U[4];
  for (int t = 0; t < 4; ++t) Z[t] = zero;
  for (int c = 0; c < KCH; ++c) {
    long off = (long)c * 1024 + cl * 64 + cq * 4;
    for (int t = 0; t < 4; ++t) *(f32x4*)&P[off + t * 16] = Z[t];   // P_c before update
    for (int t = 0; t < 4; ++t) U[t] = *(const f32x4*)&F[off + t * 16];
    scan_step(Z, Rf, Zl, U, cq, cl);                                 // P_{c+1} = A_L P_c + F_c
  }
}

__global__ __launch_bounds__(64) void scan_final_k(float* ws) {
  const float* Abar = ws + WS_ABAR;
  const float* u2 = ws + WS_U;
  const float* P = ws + WS_P;
  short* S2bf = (short*)(ws + WS_S);
  __shared__ short Zl[16 * 72];
  const int lane = threadIdx.x, cq = lane >> 4, cl = lane & 15;
  const int c = blockIdx.x;
  bf16x8 Rf[4][2];
  load_RF(Abar, Rf, cq, cl);
  f32x4 Z[4], U[4], Un[4];
  long poff = (long)c * 1024 + cl * 64 + cq * 4;
  for (int t = 0; t < 4; ++t) Z[t] = *(const f32x4*)&P[poff + t * 16];
  const float* ub = u2 + (long)c * LCH * 1024 + cl * 64 + cq * 4;
  short* sb = S2bf + (long)c * LCH * 1024 + cl * 64 + cq * 4;
  for (int t = 0; t < 4; ++t) U[t] = *(const f32x4*)(ub + t * 16);
  for (int ti = 0; ti < LCH; ++ti) {
    const float* un = ub + (ti + 1) * 1024;
    for (int t = 0; t < 4; ++t) Un[t] = *(const f32x4*)(un + t * 16);
    scan_step(Z, Rf, Zl, U, cq, cl);
    short* so = sb + ti * 1024;
    for (int t = 0; t < 4; ++t) *(u32x2*)(so + t * 16) = packbf4(Z[t]);  // states in bf16
    for (int t = 0; t < 4; ++t) U[t] = Un[t];
  }
}

// ---------------- out = states @ C^T + D*x : LDS-free, direct register fragments ----------
// Per block: 64 bt x 128 h. 4 waves, each 16 bt x 128 h. A (states) and B (C) already bf16.
__global__ __launch_bounds__(256) void out_proj_k(const float* ws, const float* Dv,
                                                  const float* x, float* out) {
  const short* Sbf = (const short*)(ws + WS_S);
  const short* Cbf = (const short*)(ws + WS_CBF);
  const int tid = threadIdx.x;
  const int wid = tid >> 6, lane = tid & 63;
  const int cq = lane >> 4, cl = lane & 15;
  const int bid = blockIdx.x;
  const int bt0 = (bid & 511) * 64 + wid * 16;
  const int h0 = (bid >> 9) * 128;

  const int abt = bt0 + cl;                      // A rows: m = cl
  const int at = abt & (TT - 1), ab = abt >> 11;
  const short* sr = Sbf + (long)(at * 16 + ab) * 64 + cq * 8;
  bf16x8 a0 = *(const bf16x8*)(sr);
  bf16x8 a1 = *(const bf16x8*)(sr + 32);

#pragma unroll
  for (int nt = 0; nt < 8; ++nt) {
    const int h = h0 + nt * 16 + cl;             // B: n = cl -> h
    const short* cr = Cbf + (long)h * 64 + cq * 8;
    bf16x8 b0 = *(const bf16x8*)(cr);
    bf16x8 b1 = *(const bf16x8*)(cr + 32);
    f32x4 acc = {0.f, 0.f, 0.f, 0.f};
    acc = mfma16(a0, b0, acc);
    acc = mfma16(a1, b1, acc);
    const float d = Dv[h];
    for (int r = 0; r < 4; ++r) {
      long obt = bt0 + cq * 4 + r;               // C/D rows: m = cq*4+r
      long idx = obt * H + h;
      out[idx] = acc[r] + d * x[idx];            // x-path kept fp32
    }
  }
}

extern "C" void kernel_launch(void* const* d_in, const int* in_sizes, int n_in,
                              void* d_out, int out_size, void* d_ws, size_t ws_size,
                              hipStream_t stream) {
  const float* x = (const float*)d_in[0];
  const float* A = (const float*)d_in[1];
  const float* Bm = (const float*)d_in[2];
  const float* Cm = (const float*)d_in[3];
  const float* Dv = (const float*)d_in[4];
  const float* ldt = (const float*)d_in[5];
  float* out = (float*)d_out;
  float* ws = (float*)d_ws;

  k0<<<dim3(64), dim3(256), 0, stream>>>(Bm, Cm, ldt, ws);
  k1<<<dim3(2 + 512), dim3(256), 0, stream>>>(x, A, ldt, ws);
  scan_local_k<<<dim3(KCH), dim3(64), 0, stream>>>(ws);
  scan_chunks_k<<<dim3(1), dim3(64), 0, stream>>>(ws);
  scan_final_k<<<dim3(KCH), dim3(64), 0, stream>>>(ws);
  out_proj_k<<<dim3(4096), dim3(256), 0, stream>>>(ws, Dv, x, out);
}